// Round 1
// baseline (2835.489 us; speedup 1.0000x reference)
//
#include <hip/hip_runtime.h>

#define NTOK 8192     // B*S
#define DDIM 1024
#define FDIM 4096
#define NEXP 8
#define TDIM 64

typedef __bf16 bf16x8 __attribute__((ext_vector_type(8)));
typedef unsigned short u16x8 __attribute__((ext_vector_type(8)));
typedef float f32x4 __attribute__((ext_vector_type(4)));

__device__ __forceinline__ unsigned short f2bf(float f) {
  unsigned u = __builtin_bit_cast(unsigned, f);
  u += 0x7fffu + ((u >> 16) & 1u);   // RNE
  return (unsigned short)(u >> 16);
}

__device__ __forceinline__ float gelu_tanh(float h) {
  // jax.nn.gelu default: approximate=True (tanh form)
  float u = 0.7978845608028654f * (h + 0.044715f * h * h * h);
  return 0.5f * h * (1.0f + tanhf(u));
}

// ---------------- gating: logits, top-2, aux sums, expert lists ----------------
__global__ __launch_bounds__(256) void gate_kernel(
    const float* __restrict__ x, const float* __restrict__ task,
    const float* __restrict__ alpha_p,
    const float* __restrict__ Wg_in, const float* __restrict__ bg_in,
    const float* __restrict__ Wg_task, const float* __restrict__ bg_task,
    int* __restrict__ cnt, float* __restrict__ wsum,
    int* __restrict__ tok_list, float* __restrict__ wt_list)
{
  __shared__ float s_wsum[NEXP];
  int tid = threadIdx.x;
  if (tid < NEXP) s_wsum[tid] = 0.0f;
  __syncthreads();

  int lane = tid & 63;
  int wid  = tid >> 6;
  int tok  = blockIdx.x * 4 + wid;       // one token per wave, grid = NTOK/4
  float a  = alpha_p[0];

  const float* xr = x + (size_t)tok * DDIM;
  float accd[8] = {0,0,0,0,0,0,0,0};
#pragma unroll
  for (int i = 0; i < DDIM/64; ++i) {
    int d = lane + 64*i;
    float xv = xr[d];
    f32x4 wa = *(const f32x4*)(Wg_in + (size_t)d*8);
    f32x4 wb = *(const f32x4*)(Wg_in + (size_t)d*8 + 4);
#pragma unroll
    for (int j = 0; j < 4; ++j) {
      accd[j]   = fmaf(xv, wa[j], accd[j]);
      accd[4+j] = fmaf(xv, wb[j], accd[4+j]);
    }
  }
  float part[8];
  {
    int d = lane;                         // TDIM == 64 exactly
    float tv = task[(size_t)tok*TDIM + d];
    f32x4 wa = *(const f32x4*)(Wg_task + (size_t)d*8);
    f32x4 wb = *(const f32x4*)(Wg_task + (size_t)d*8 + 4);
#pragma unroll
    for (int j = 0; j < 4; ++j) {
      part[j]   = (1.0f-a)*accd[j]   + a*(tv*wa[j]);
      part[4+j] = (1.0f-a)*accd[4+j] + a*(tv*wb[j]);
    }
  }
#pragma unroll
  for (int e = 0; e < 8; ++e) {
#pragma unroll
    for (int m = 1; m < 64; m <<= 1) part[e] += __shfl_xor(part[e], m);
  }

  if (lane == 0) {
    float lg[8];
#pragma unroll
    for (int e = 0; e < 8; ++e) lg[e] = part[e] + (1.0f-a)*bg_in[e] + a*bg_task[e];
    // top-2, ties -> lower index (strict > keeps lowest)
    int e0 = 0;
#pragma unroll
    for (int e = 1; e < 8; ++e) if (lg[e] > lg[e0]) e0 = e;
    int e1 = (e0 == 0) ? 1 : 0;
#pragma unroll
    for (int e = 0; e < 8; ++e) if (e != e0 && lg[e] > lg[e1]) e1 = e;
    // full softmax for aux loss
    float mx = lg[0];
#pragma unroll
    for (int e = 1; e < 8; ++e) mx = fmaxf(mx, lg[e]);
    float p[8], s = 0.0f;
#pragma unroll
    for (int e = 0; e < 8; ++e) { p[e] = __expf(lg[e] - mx); s += p[e]; }
    float inv = 1.0f / s;
#pragma unroll
    for (int e = 0; e < 8; ++e) atomicAdd(&s_wsum[e], p[e] * inv);
    // combine weights: softmax over the two selected logits
    float p1 = __expf(lg[e1] - lg[e0]);
    float w0 = 1.0f / (1.0f + p1);
    float w1 = p1 * w0;
    int pos0 = atomicAdd(&cnt[e0], 1);
    tok_list[e0*NTOK + pos0] = tok; wt_list[e0*NTOK + pos0] = w0;
    int pos1 = atomicAdd(&cnt[e1], 1);
    tok_list[e1*NTOK + pos1] = tok; wt_list[e1*NTOK + pos1] = w1;
  }
  __syncthreads();
  if (tid < NEXP) atomicAdd(&wsum[tid], s_wsum[tid]);
}

// ---------------- finalize: offsets prefix + l_aux ----------------
__global__ void finalize_kernel(const int* __restrict__ cnt, const float* __restrict__ wsum,
                                int* __restrict__ offs, float* __restrict__ laux)
{
  if (threadIdx.x == 0) {
    int o = 0; float l = 0.0f;
    for (int e = 0; e < NEXP; ++e) {
      offs[e] = o; o += cnt[e];
      l += (wsum[e] * (1.0f/NTOK)) * ((float)cnt[e] * (1.0f/NTOK));
    }
    *laux = l;   // mean(avg_w*avg_c)*E == sum_e avg_w*avg_c
  }
}

// ---------------- GEMM1: H = gelu(gather(X) @ W1[e] + b1[e]) ----------------
// 128x128 tile, BK=32, 4 waves (2x2), mfma_f32_16x16x32_bf16.
// LDS row stride 40 ushorts (80B): 16B-aligned frags, 2-way bank alias (free).
__global__ __launch_bounds__(256) void gemm1_kernel(
    const float* __restrict__ X, const float* __restrict__ W1,
    const float* __restrict__ b1,
    const int* __restrict__ cnt, const int* __restrict__ offs,
    const int* __restrict__ tok_list,
    unsigned short* __restrict__ H)
{
  int e  = blockIdx.z;
  int ce = cnt[e];
  int m0 = blockIdx.x * 128;
  if (m0 >= ce) return;
  int n0 = blockIdx.y * 128;
  int off = offs[e];
  const float* We = W1 + (size_t)e * DDIM * FDIM;
  const float* be = b1 + (size_t)e * FDIM;

  __shared__ __align__(16) unsigned short sA[128*40];
  __shared__ __align__(16) unsigned short sB[128*40];
  __shared__ int s_tok[128];

  int tid = threadIdx.x;
  if (tid < 128) {
    int idx = m0 + tid;
    s_tok[tid] = (idx < ce) ? tok_list[e*NTOK + idx] : -1;
  }
  __syncthreads();

  // A staging: 4 rounds, thread -> (row = tid>>3 + 32i, colchunk = tid&7)
  int ac  = tid & 7;
  int ar0 = tid >> 3;
  const float* aptr[4]; bool av[4];
#pragma unroll
  for (int i = 0; i < 4; ++i) {
    int r = ar0 + 32*i;
    int t = s_tok[r];
    av[i]   = (t >= 0);
    aptr[i] = av[i] ? (X + (size_t)t * DDIM + ac*4) : X;
  }
  // B staging: 4 rounds, thread -> (k = tid>>5 + 8i, nchunk = tid&31)
  int bc  = tid & 31;
  int bk0 = tid >> 5;

  f32x4 acc[4][4];
#pragma unroll
  for (int mi = 0; mi < 4; ++mi)
#pragma unroll
    for (int ni = 0; ni < 4; ++ni) acc[mi][ni] = (f32x4){0.f,0.f,0.f,0.f};

  int lane = tid & 63, wid = tid >> 6;
  int wr = wid >> 1, wc = wid & 1;
  int q = lane & 15, g = lane >> 4;
  const int arow = (wr*64 + q)*40 + g*8;
  const int brow = (wc*64 + q)*40 + g*8;

  for (int k0 = 0; k0 < DDIM; k0 += 32) {
#pragma unroll
    for (int i = 0; i < 4; ++i) {   // stage A (gather + convert)
      f32x4 v = av[i] ? *(const f32x4*)(aptr[i] + k0) : (f32x4){0.f,0.f,0.f,0.f};
      unsigned short* d = &sA[(ar0 + 32*i)*40 + ac*4];
      d[0]=f2bf(v[0]); d[1]=f2bf(v[1]); d[2]=f2bf(v[2]); d[3]=f2bf(v[3]);
    }
#pragma unroll
    for (int i = 0; i < 4; ++i) {   // stage B transposed: LDS[n][k]
      int k = bk0 + 8*i;
      f32x4 v = *(const f32x4*)(We + (size_t)(k0+k)*FDIM + n0 + bc*4);
      sB[(bc*4+0)*40 + k] = f2bf(v[0]);
      sB[(bc*4+1)*40 + k] = f2bf(v[1]);
      sB[(bc*4+2)*40 + k] = f2bf(v[2]);
      sB[(bc*4+3)*40 + k] = f2bf(v[3]);
    }
    __syncthreads();
    bf16x8 af[4], bfr[4];
#pragma unroll
    for (int mi = 0; mi < 4; ++mi) af[mi]  = __builtin_bit_cast(bf16x8, *(const u16x8*)&sA[arow + mi*640]);
#pragma unroll
    for (int ni = 0; ni < 4; ++ni) bfr[ni] = __builtin_bit_cast(bf16x8, *(const u16x8*)&sB[brow + ni*640]);
#pragma unroll
    for (int mi = 0; mi < 4; ++mi)
#pragma unroll
      for (int ni = 0; ni < 4; ++ni)
        acc[mi][ni] = __builtin_amdgcn_mfma_f32_16x16x32_bf16(af[mi], bfr[ni], acc[mi][ni], 0, 0, 0);
    __syncthreads();
  }

  // epilogue: bias + gelu -> H (bf16). C/D: col=lane&15, row=(lane>>4)*4+reg.
#pragma unroll
  for (int mi = 0; mi < 4; ++mi) {
    int rit = wr*64 + mi*16 + g*4;
#pragma unroll
    for (int j = 0; j < 4; ++j) {
      int r = m0 + rit + j;
      if (r >= ce) continue;
      size_t hrow = (size_t)(off + r) * FDIM;
#pragma unroll
      for (int ni = 0; ni < 4; ++ni) {
        int n = n0 + wc*64 + ni*16 + q;
        float h = acc[mi][ni][j] + be[n];
        H[hrow + n] = f2bf(gelu_tanh(h));
      }
    }
  }
}

// ---------------- GEMM2: out[tok] += w * (H @ W2[e] + b2[e]) ----------------
__global__ __launch_bounds__(256) void gemm2_kernel(
    const unsigned short* __restrict__ H, const float* __restrict__ W2,
    const float* __restrict__ b2,
    const int* __restrict__ cnt, const int* __restrict__ offs,
    const int* __restrict__ tok_list, const float* __restrict__ wt_list,
    float* __restrict__ out)
{
  int e  = blockIdx.z;
  int ce = cnt[e];
  int m0 = blockIdx.x * 128;
  if (m0 >= ce) return;
  int n0 = blockIdx.y * 128;
  int off = offs[e];
  const float* We = W2 + (size_t)e * FDIM * DDIM;
  const float* be = b2 + (size_t)e * DDIM;

  __shared__ __align__(16) unsigned short sA[128*40];
  __shared__ __align__(16) unsigned short sB[128*40];
  __shared__ int   s_tok[128];
  __shared__ float s_wt[128];

  int tid = threadIdx.x;
  if (tid < 128) {
    int idx = m0 + tid;
    bool v = (idx < ce);
    s_tok[tid] = v ? tok_list[e*NTOK + idx] : 0;
    s_wt[tid]  = v ? wt_list[e*NTOK + idx] : 0.0f;
  }
  __syncthreads();

  // A staging (bf16 H, no convert): 2 rounds, row = tid>>2 + 64i, chunk = tid&3
  int ac  = tid & 3;
  int ar0 = tid >> 2;
  const unsigned short* aptr[2]; bool av[2];
#pragma unroll
  for (int i = 0; i < 2; ++i) {
    int r = ar0 + 64*i;
    av[i]   = (m0 + r < ce);
    aptr[i] = H + (size_t)(off + m0 + r) * FDIM + ac*8;
  }
  int bc  = tid & 31;
  int bk0 = tid >> 5;

  f32x4 acc[4][4];
#pragma unroll
  for (int mi = 0; mi < 4; ++mi)
#pragma unroll
    for (int ni = 0; ni < 4; ++ni) acc[mi][ni] = (f32x4){0.f,0.f,0.f,0.f};

  int lane = tid & 63, wid = tid >> 6;
  int wr = wid >> 1, wc = wid & 1;
  int q = lane & 15, g = lane >> 4;
  const int arow = (wr*64 + q)*40 + g*8;
  const int brow = (wc*64 + q)*40 + g*8;
  const u16x8 z8 = {0,0,0,0,0,0,0,0};

  for (int k0 = 0; k0 < FDIM; k0 += 32) {
#pragma unroll
    for (int i = 0; i < 2; ++i) {   // stage A
      u16x8 v = av[i] ? *(const u16x8*)(aptr[i] + k0) : z8;
      *(u16x8*)&sA[(ar0 + 64*i)*40 + ac*8] = v;
    }
#pragma unroll
    for (int i = 0; i < 4; ++i) {   // stage B transposed
      int k = bk0 + 8*i;
      f32x4 v = *(const f32x4*)(We + (size_t)(k0+k)*DDIM + n0 + bc*4);
      sB[(bc*4+0)*40 + k] = f2bf(v[0]);
      sB[(bc*4+1)*40 + k] = f2bf(v[1]);
      sB[(bc*4+2)*40 + k] = f2bf(v[2]);
      sB[(bc*4+3)*40 + k] = f2bf(v[3]);
    }
    __syncthreads();
    bf16x8 af[4], bfr[4];
#pragma unroll
    for (int mi = 0; mi < 4; ++mi) af[mi]  = __builtin_bit_cast(bf16x8, *(const u16x8*)&sA[arow + mi*640]);
#pragma unroll
    for (int ni = 0; ni < 4; ++ni) bfr[ni] = __builtin_bit_cast(bf16x8, *(const u16x8*)&sB[brow + ni*640]);
#pragma unroll
    for (int mi = 0; mi < 4; ++mi)
#pragma unroll
      for (int ni = 0; ni < 4; ++ni)
        acc[mi][ni] = __builtin_amdgcn_mfma_f32_16x16x32_bf16(af[mi], bfr[ni], acc[mi][ni], 0, 0, 0);
    __syncthreads();
  }

  // epilogue: weighted scatter-add into out
#pragma unroll
  for (int mi = 0; mi < 4; ++mi) {
    int rit = wr*64 + mi*16 + g*4;
#pragma unroll
    for (int j = 0; j < 4; ++j) {
      int r = rit + j;
      if (m0 + r >= ce) continue;
      int tok = s_tok[r];
      float w = s_wt[r];
      float* orow = out + (size_t)tok * DDIM;
#pragma unroll
      for (int ni = 0; ni < 4; ++ni) {
        int n = n0 + wc*64 + ni*16 + q;
        float y = acc[mi][ni][j] + be[n];
        unsafeAtomicAdd(&orow[n], w * y);
      }
    }
  }
}

// ---------------- launch ----------------
extern "C" void kernel_launch(void* const* d_in, const int* in_sizes, int n_in,
                              void* d_out, int out_size, void* d_ws, size_t ws_size,
                              hipStream_t stream)
{
  const float* x       = (const float*)d_in[0];
  const float* task    = (const float*)d_in[1];
  const float* alpha   = (const float*)d_in[2];
  const float* Wg_in   = (const float*)d_in[3];
  const float* bg_in   = (const float*)d_in[4];
  const float* Wg_task = (const float*)d_in[5];
  const float* bg_task = (const float*)d_in[6];
  const float* W1      = (const float*)d_in[7];
  const float* b1      = (const float*)d_in[8];
  const float* W2      = (const float*)d_in[9];
  const float* b2      = (const float*)d_in[10];
  float* out = (float*)d_out;

  // ws layout: [0)cnt[8] [32)wsum[8] [64)offs[8] [128)tok_list[8][8192] (+256KB)
  //            wt_list[8][8192] (+256KB), H bf16[16384][4096] @1MB (128MiB)
  char* ws = (char*)d_ws;
  int*   cnt      = (int*)(ws + 0);
  float* wsum     = (float*)(ws + 32);
  int*   offs     = (int*)(ws + 64);
  int*   tok_list = (int*)(ws + 128);
  float* wt_list  = (float*)(ws + 128 + NTOK*NEXP*4);
  unsigned short* H = (unsigned short*)(ws + (1 << 20));

  hipMemsetAsync(d_out, 0, (size_t)out_size * sizeof(float), stream);
  hipMemsetAsync(ws, 0, 128, stream);
  gate_kernel<<<NTOK/4, 256, 0, stream>>>(x, task, alpha, Wg_in, bg_in, Wg_task, bg_task,
                                          cnt, wsum, tok_list, wt_list);
  finalize_kernel<<<1, 64, 0, stream>>>(cnt, wsum, offs, out + (size_t)NTOK*DDIM);
  gemm1_kernel<<<dim3(NTOK/128, FDIM/128, NEXP), 256, 0, stream>>>(x, W1, b1, cnt, offs, tok_list, H);
  gemm2_kernel<<<dim3(NTOK/128, DDIM/128, NEXP), 256, 0, stream>>>(H, W2, b2, cnt, offs, tok_list, wt_list, out);
}

// Round 2
// 1514.612 us; speedup vs baseline: 1.8721x; 1.8721x over previous
//
#include <hip/hip_runtime.h>

#define NTOK 8192     // B*S
#define DDIM 1024
#define FDIM 4096
#define NEXP 8
#define TDIM 64

typedef __bf16 bf16x8 __attribute__((ext_vector_type(8)));
typedef unsigned short u16x8 __attribute__((ext_vector_type(8)));
typedef float f32x4 __attribute__((ext_vector_type(4)));

__device__ __forceinline__ float gelu_tanh(float h) {
  // jax.nn.gelu approximate=True; tanh(u) = 1 - 2/(e^{2u}+1) (saturates correctly)
  float u = 0.7978845608028654f * (h + 0.044715f * h * h * h);
  float e = __expf(2.0f * u);
  return 0.5f * h * (2.0f - 2.0f / (e + 1.0f)) ;
}

// ---------------- gating: logits, top-2, aux sums, expert lists ----------------
__global__ __launch_bounds__(256) void gate_kernel(
    const float* __restrict__ x, const float* __restrict__ task,
    const float* __restrict__ alpha_p,
    const float* __restrict__ Wg_in, const float* __restrict__ bg_in,
    const float* __restrict__ Wg_task, const float* __restrict__ bg_task,
    int* __restrict__ cnt, float* __restrict__ wsum,
    int* __restrict__ tok_list, float* __restrict__ wt_list)
{
  __shared__ float s_wsum[NEXP];
  int tid = threadIdx.x;
  if (tid < NEXP) s_wsum[tid] = 0.0f;
  __syncthreads();

  int lane = tid & 63;
  int wid  = tid >> 6;
  int tok  = blockIdx.x * 4 + wid;       // one token per wave, grid = NTOK/4
  float a  = alpha_p[0];

  const float* xr = x + (size_t)tok * DDIM;
  float accd[8] = {0,0,0,0,0,0,0,0};
#pragma unroll
  for (int i = 0; i < DDIM/64; ++i) {
    int d = lane + 64*i;
    float xv = xr[d];
    f32x4 wa = *(const f32x4*)(Wg_in + (size_t)d*8);
    f32x4 wb = *(const f32x4*)(Wg_in + (size_t)d*8 + 4);
#pragma unroll
    for (int j = 0; j < 4; ++j) {
      accd[j]   = fmaf(xv, wa[j], accd[j]);
      accd[4+j] = fmaf(xv, wb[j], accd[4+j]);
    }
  }
  float part[8];
  {
    int d = lane;                         // TDIM == 64 exactly
    float tv = task[(size_t)tok*TDIM + d];
    f32x4 wa = *(const f32x4*)(Wg_task + (size_t)d*8);
    f32x4 wb = *(const f32x4*)(Wg_task + (size_t)d*8 + 4);
#pragma unroll
    for (int j = 0; j < 4; ++j) {
      part[j]   = (1.0f-a)*accd[j]   + a*(tv*wa[j]);
      part[4+j] = (1.0f-a)*accd[4+j] + a*(tv*wb[j]);
    }
  }
#pragma unroll
  for (int e = 0; e < 8; ++e) {
#pragma unroll
    for (int m = 1; m < 64; m <<= 1) part[e] += __shfl_xor(part[e], m);
  }

  if (lane == 0) {
    float lg[8];
#pragma unroll
    for (int e = 0; e < 8; ++e) lg[e] = part[e] + (1.0f-a)*bg_in[e] + a*bg_task[e];
    // top-2, ties -> lower index (strict > keeps lowest)
    int e0 = 0;
#pragma unroll
    for (int e = 1; e < 8; ++e) if (lg[e] > lg[e0]) e0 = e;
    int e1 = (e0 == 0) ? 1 : 0;
#pragma unroll
    for (int e = 0; e < 8; ++e) if (e != e0 && lg[e] > lg[e1]) e1 = e;
    // full softmax for aux loss
    float mx = lg[0];
#pragma unroll
    for (int e = 1; e < 8; ++e) mx = fmaxf(mx, lg[e]);
    float p[8], s = 0.0f;
#pragma unroll
    for (int e = 0; e < 8; ++e) { p[e] = __expf(lg[e] - mx); s += p[e]; }
    float inv = 1.0f / s;
#pragma unroll
    for (int e = 0; e < 8; ++e) atomicAdd(&s_wsum[e], p[e] * inv);
    // combine weights: softmax over the two selected logits
    float p1 = __expf(lg[e1] - lg[e0]);
    float w0 = 1.0f / (1.0f + p1);
    float w1 = p1 * w0;
    int pos0 = atomicAdd(&cnt[e0], 1);
    tok_list[e0*NTOK + pos0] = tok; wt_list[e0*NTOK + pos0] = w0;
    int pos1 = atomicAdd(&cnt[e1], 1);
    tok_list[e1*NTOK + pos1] = tok; wt_list[e1*NTOK + pos1] = w1;
  }
  __syncthreads();
  if (tid < NEXP) atomicAdd(&wsum[tid], s_wsum[tid]);
}

// ---------------- finalize: offsets prefix + l_aux ----------------
__global__ void finalize_kernel(const int* __restrict__ cnt, const float* __restrict__ wsum,
                                int* __restrict__ offs, float* __restrict__ laux)
{
  if (threadIdx.x == 0) {
    int o = 0; float l = 0.0f;
    for (int e = 0; e < NEXP; ++e) {
      offs[e] = o; o += cnt[e];
      l += (wsum[e] * (1.0f/NTOK)) * ((float)cnt[e] * (1.0f/NTOK));
    }
    *laux = l;   // mean(avg_w*avg_c)*E == sum_e avg_w*avg_c
  }
}

// ---------------- GEMM1: H = gelu(gather(X) @ W1[e] + b1[e]) ----------------
// 128x128 tile, BK=32, 4 waves (2x2), mfma_f32_16x16x32_bf16.
// LDS row stride 40 ushorts (80B = 5 quad-banks): all b128 read/write
// patterns land on (5*row + chunk) mod 8 quad-groups, gcd(5,8)=1 -> balanced.
__global__ __launch_bounds__(256) void gemm1_kernel(
    const float* __restrict__ X, const float* __restrict__ W1,
    const float* __restrict__ b1,
    const int* __restrict__ cnt, const int* __restrict__ offs,
    const int* __restrict__ tok_list,
    unsigned short* __restrict__ H)
{
  int e  = blockIdx.z;
  int ce = cnt[e];
  int m0 = blockIdx.x * 128;
  if (m0 >= ce) return;
  int n0 = blockIdx.y * 128;
  int off = offs[e];
  const float* We = W1 + (size_t)e * DDIM * FDIM;
  const float* be = b1 + (size_t)e * FDIM;

  __shared__ __align__(16) unsigned short sA[128*40];
  __shared__ __align__(16) unsigned short sB[128*40];
  __shared__ int s_tok[128];

  int tid = threadIdx.x;
  if (tid < 128) {
    int idx = m0 + tid;
    s_tok[tid] = (idx < ce) ? tok_list[e*NTOK + idx] : -1;
  }
  __syncthreads();

  // A staging: thread -> (kchunk kcA = tid&3, rows rA and rA+64)
  int kcA = tid & 3, rA = tid >> 2;
  const float* aptr[2]; bool av[2];
#pragma unroll
  for (int i = 0; i < 2; ++i) {
    int t = s_tok[rA + 64*i];
    av[i]   = (t >= 0);
    aptr[i] = av[i] ? (X + (size_t)t * DDIM + kcA*8) : X;
  }
  // B staging: thread -> (n = nB and nB+64, kchunk kcB = tid>>6)
  int nB = tid & 63, kcB = tid >> 6;

  f32x4 acc[4][4];
#pragma unroll
  for (int mi = 0; mi < 4; ++mi)
#pragma unroll
    for (int ni = 0; ni < 4; ++ni) acc[mi][ni] = (f32x4){0.f,0.f,0.f,0.f};

  int lane = tid & 63, wid = tid >> 6;
  int wr = wid >> 1, wc = wid & 1;
  int q = lane & 15, g = lane >> 4;
  const int arow = (wr*64 + q)*40 + g*8;
  const int brow = (wc*64 + q)*40 + g*8;

  for (int k0 = 0; k0 < DDIM; k0 += 32) {
    // stage A (gather + hw cvt + one b128 store per chunk)
#pragma unroll
    for (int i = 0; i < 2; ++i) {
      f32x4 va = {0.f,0.f,0.f,0.f}, vb = {0.f,0.f,0.f,0.f};
      if (av[i]) { va = *(const f32x4*)(aptr[i] + k0); vb = *(const f32x4*)(aptr[i] + k0 + 4); }
      bf16x8 bv;
      bv[0]=(__bf16)va[0]; bv[1]=(__bf16)va[1]; bv[2]=(__bf16)va[2]; bv[3]=(__bf16)va[3];
      bv[4]=(__bf16)vb[0]; bv[5]=(__bf16)vb[1]; bv[6]=(__bf16)vb[2]; bv[7]=(__bf16)vb[3];
      *(bf16x8*)&sA[(rA + 64*i)*40 + kcA*8] = bv;
    }
    // stage B transposed (8 coalesced dword loads per chunk + one b128 store)
    {
      const float* bsrc = We + (size_t)(k0 + kcB*8) * FDIM + n0 + nB;
#pragma unroll
      for (int i = 0; i < 2; ++i) {
        bf16x8 bv;
#pragma unroll
        for (int kk = 0; kk < 8; ++kk) bv[kk] = (__bf16)bsrc[(size_t)kk*FDIM + 64*i];
        *(bf16x8*)&sB[(nB + 64*i)*40 + kcB*8] = bv;
      }
    }
    __syncthreads();
    bf16x8 af[4], bfr[4];
#pragma unroll
    for (int mi = 0; mi < 4; ++mi) af[mi]  = *(const bf16x8*)&sA[arow + mi*640];
#pragma unroll
    for (int ni = 0; ni < 4; ++ni) bfr[ni] = *(const bf16x8*)&sB[brow + ni*640];
#pragma unroll
    for (int mi = 0; mi < 4; ++mi)
#pragma unroll
      for (int ni = 0; ni < 4; ++ni)
        acc[mi][ni] = __builtin_amdgcn_mfma_f32_16x16x32_bf16(af[mi], bfr[ni], acc[mi][ni], 0, 0, 0);
    __syncthreads();
  }

  // epilogue: bias + gelu -> H (bf16). C/D: col=lane&15, row=(lane>>4)*4+reg.
#pragma unroll
  for (int mi = 0; mi < 4; ++mi) {
    int rit = wr*64 + mi*16 + g*4;
#pragma unroll
    for (int j = 0; j < 4; ++j) {
      int r = m0 + rit + j;
      if (r >= ce) continue;
      size_t hrow = (size_t)(off + r) * FDIM;
#pragma unroll
      for (int ni = 0; ni < 4; ++ni) {
        int n = n0 + wc*64 + ni*16 + q;
        float h = acc[mi][ni][j] + be[n];
        H[hrow + n] = __builtin_bit_cast(unsigned short, (__bf16)gelu_tanh(h));
      }
    }
  }
}

// ---------------- GEMM2: out[tok] += w * (H @ W2[e] + b2[e]) ----------------
__global__ __launch_bounds__(256) void gemm2_kernel(
    const unsigned short* __restrict__ H, const float* __restrict__ W2,
    const float* __restrict__ b2,
    const int* __restrict__ cnt, const int* __restrict__ offs,
    const int* __restrict__ tok_list, const float* __restrict__ wt_list,
    float* __restrict__ out)
{
  int e  = blockIdx.z;
  int ce = cnt[e];
  int m0 = blockIdx.x * 128;
  if (m0 >= ce) return;
  int n0 = blockIdx.y * 128;
  int off = offs[e];
  const float* We = W2 + (size_t)e * FDIM * DDIM;
  const float* be = b2 + (size_t)e * DDIM;

  __shared__ __align__(16) unsigned short sA[128*40];
  __shared__ __align__(16) unsigned short sB[128*40];
  __shared__ int   s_tok[128];
  __shared__ float s_wt[128];

  int tid = threadIdx.x;
  if (tid < 128) {
    int idx = m0 + tid;
    bool v = (idx < ce);
    s_tok[tid] = v ? tok_list[e*NTOK + idx] : 0;
    s_wt[tid]  = v ? wt_list[e*NTOK + idx] : 0.0f;
  }
  __syncthreads();

  // A staging (bf16 H): thread -> (kchunk kcA = tid&3, rows rA and rA+64)
  int kcA = tid & 3, rA = tid >> 2;
  const unsigned short* aptr[2]; bool av[2];
#pragma unroll
  for (int i = 0; i < 2; ++i) {
    int r = rA + 64*i;
    av[i]   = (m0 + r < ce);
    aptr[i] = H + (size_t)(off + m0 + r) * FDIM + kcA*8;
  }
  int nB = tid & 63, kcB = tid >> 6;

  f32x4 acc[4][4];
#pragma unroll
  for (int mi = 0; mi < 4; ++mi)
#pragma unroll
    for (int ni = 0; ni < 4; ++ni) acc[mi][ni] = (f32x4){0.f,0.f,0.f,0.f};

  int lane = tid & 63, wid = tid >> 6;
  int wr = wid >> 1, wc = wid & 1;
  int q = lane & 15, g = lane >> 4;
  const int arow = (wr*64 + q)*40 + g*8;
  const int brow = (wc*64 + q)*40 + g*8;
  const u16x8 z8 = {0,0,0,0,0,0,0,0};

  for (int k0 = 0; k0 < FDIM; k0 += 32) {
#pragma unroll
    for (int i = 0; i < 2; ++i) {   // stage A (b128 in, b128 out)
      u16x8 v = av[i] ? *(const u16x8*)(aptr[i] + k0) : z8;
      *(u16x8*)&sA[(rA + 64*i)*40 + kcA*8] = v;
    }
    {                               // stage B transposed
      const float* bsrc = We + (size_t)(k0 + kcB*8) * DDIM + n0 + nB;
#pragma unroll
      for (int i = 0; i < 2; ++i) {
        bf16x8 bv;
#pragma unroll
        for (int kk = 0; kk < 8; ++kk) bv[kk] = (__bf16)bsrc[(size_t)kk*DDIM + 64*i];
        *(bf16x8*)&sB[(nB + 64*i)*40 + kcB*8] = bv;
      }
    }
    __syncthreads();
    bf16x8 af[4], bfr[4];
#pragma unroll
    for (int mi = 0; mi < 4; ++mi) af[mi]  = *(const bf16x8*)&sA[arow + mi*640];
#pragma unroll
    for (int ni = 0; ni < 4; ++ni) bfr[ni] = *(const bf16x8*)&sB[brow + ni*640];
#pragma unroll
    for (int mi = 0; mi < 4; ++mi)
#pragma unroll
      for (int ni = 0; ni < 4; ++ni)
        acc[mi][ni] = __builtin_amdgcn_mfma_f32_16x16x32_bf16(af[mi], bfr[ni], acc[mi][ni], 0, 0, 0);
    __syncthreads();
  }

  // epilogue: weighted scatter-add into out
#pragma unroll
  for (int mi = 0; mi < 4; ++mi) {
    int rit = wr*64 + mi*16 + g*4;
#pragma unroll
    for (int j = 0; j < 4; ++j) {
      int r = rit + j;
      if (m0 + r >= ce) continue;
      int tok = s_tok[r];
      float w = s_wt[r];
      float* orow = out + (size_t)tok * DDIM;
#pragma unroll
      for (int ni = 0; ni < 4; ++ni) {
        int n = n0 + wc*64 + ni*16 + q;
        float y = acc[mi][ni][j] + be[n];
        unsafeAtomicAdd(&orow[n], w * y);
      }
    }
  }
}

// ---------------- launch ----------------
extern "C" void kernel_launch(void* const* d_in, const int* in_sizes, int n_in,
                              void* d_out, int out_size, void* d_ws, size_t ws_size,
                              hipStream_t stream)
{
  const float* x       = (const float*)d_in[0];
  const float* task    = (const float*)d_in[1];
  const float* alpha   = (const float*)d_in[2];
  const float* Wg_in   = (const float*)d_in[3];
  const float* bg_in   = (const float*)d_in[4];
  const float* Wg_task = (const float*)d_in[5];
  const float* bg_task = (const float*)d_in[6];
  const float* W1      = (const float*)d_in[7];
  const float* b1      = (const float*)d_in[8];
  const float* W2      = (const float*)d_in[9];
  const float* b2      = (const float*)d_in[10];
  float* out = (float*)d_out;

  // ws layout: [0)cnt[8] [32)wsum[8] [64)offs[8] [128)tok_list[8][8192] (+256KB)
  //            wt_list[8][8192] (+256KB), H bf16[16384][4096] @1MB (128MiB)
  char* ws = (char*)d_ws;
  int*   cnt      = (int*)(ws + 0);
  float* wsum     = (float*)(ws + 32);
  int*   offs     = (int*)(ws + 64);
  int*   tok_list = (int*)(ws + 128);
  float* wt_list  = (float*)(ws + 128 + NTOK*NEXP*4);
  unsigned short* H = (unsigned short*)(ws + (1 << 20));

  hipMemsetAsync(d_out, 0, (size_t)out_size * sizeof(float), stream);
  hipMemsetAsync(ws, 0, 128, stream);
  gate_kernel<<<NTOK/4, 256, 0, stream>>>(x, task, alpha, Wg_in, bg_in, Wg_task, bg_task,
                                          cnt, wsum, tok_list, wt_list);
  finalize_kernel<<<1, 64, 0, stream>>>(cnt, wsum, offs, out + (size_t)NTOK*DDIM);
  gemm1_kernel<<<dim3(NTOK/128, FDIM/128, NEXP), 256, 0, stream>>>(x, W1, b1, cnt, offs, tok_list, H);
  gemm2_kernel<<<dim3(NTOK/128, DDIM/128, NEXP), 256, 0, stream>>>(H, W2, b2, cnt, offs, tok_list, wt_list, out);
}

// Round 3
// 1128.391 us; speedup vs baseline: 2.5129x; 1.3423x over previous
//
#include <hip/hip_runtime.h>

#define NTOK 8192     // B*S
#define DDIM 1024
#define FDIM 4096
#define NEXP 8
#define TDIM 64

// ws layout (fast path):
#define H_OFF   (1u<<20)
#define W1B_OFF (H_OFF + 134217728u)      // H: 16384 x 4096 bf16 = 128 MiB
#define W2B_OFF (W1B_OFF + 67108864u)     // W1b: 64 MiB
#define XB_OFF  (W2B_OFF + 67108864u)     // W2b: 64 MiB
#define FULL_WS (XB_OFF + 16777216u)      // Xb: 16 MiB -> total 286,261,248 B

typedef __bf16 bf16x8 __attribute__((ext_vector_type(8)));
typedef unsigned short u16x8 __attribute__((ext_vector_type(8)));
typedef unsigned short u16x4 __attribute__((ext_vector_type(4)));
typedef float f32x4 __attribute__((ext_vector_type(4)));

__device__ __forceinline__ float gelu_tanh(float h) {
  // jax.nn.gelu approximate=True; tanh(u) = 1 - 2/(e^{2u}+1) (saturates correctly)
  float u = 0.7978845608028654f * (h + 0.044715f * h * h * h);
  float e = __expf(2.0f * u);
  return 0.5f * h * (2.0f - 2.0f / (e + 1.0f));
}

__device__ __forceinline__ void glds16(const void* g, void* l) {
  __builtin_amdgcn_global_load_lds((const __attribute__((address_space(1))) void*)g,
                                   (__attribute__((address_space(3))) void*)l, 16, 0, 0);
}

// ---------------- gating: logits, top-2, aux sums, expert lists ----------------
__global__ __launch_bounds__(256) void gate_kernel(
    const float* __restrict__ x, const float* __restrict__ task,
    const float* __restrict__ alpha_p,
    const float* __restrict__ Wg_in, const float* __restrict__ bg_in,
    const float* __restrict__ Wg_task, const float* __restrict__ bg_task,
    int* __restrict__ cnt, float* __restrict__ wsum,
    int* __restrict__ tok_list, float* __restrict__ wt_list)
{
  __shared__ float s_wsum[NEXP];
  int tid = threadIdx.x;
  if (tid < NEXP) s_wsum[tid] = 0.0f;
  __syncthreads();

  int lane = tid & 63;
  int wid  = tid >> 6;
  int tok  = blockIdx.x * 4 + wid;
  float a  = alpha_p[0];

  const float* xr = x + (size_t)tok * DDIM;
  float accd[8] = {0,0,0,0,0,0,0,0};
#pragma unroll
  for (int i = 0; i < DDIM/64; ++i) {
    int d = lane + 64*i;
    float xv = xr[d];
    f32x4 wa = *(const f32x4*)(Wg_in + (size_t)d*8);
    f32x4 wb = *(const f32x4*)(Wg_in + (size_t)d*8 + 4);
#pragma unroll
    for (int j = 0; j < 4; ++j) {
      accd[j]   = fmaf(xv, wa[j], accd[j]);
      accd[4+j] = fmaf(xv, wb[j], accd[4+j]);
    }
  }
  float part[8];
  {
    int d = lane;                         // TDIM == 64 exactly
    float tv = task[(size_t)tok*TDIM + d];
    f32x4 wa = *(const f32x4*)(Wg_task + (size_t)d*8);
    f32x4 wb = *(const f32x4*)(Wg_task + (size_t)d*8 + 4);
#pragma unroll
    for (int j = 0; j < 4; ++j) {
      part[j]   = (1.0f-a)*accd[j]   + a*(tv*wa[j]);
      part[4+j] = (1.0f-a)*accd[4+j] + a*(tv*wb[j]);
    }
  }
#pragma unroll
  for (int e = 0; e < 8; ++e) {
#pragma unroll
    for (int m = 1; m < 64; m <<= 1) part[e] += __shfl_xor(part[e], m);
  }

  if (lane == 0) {
    float lg[8];
#pragma unroll
    for (int e = 0; e < 8; ++e) lg[e] = part[e] + (1.0f-a)*bg_in[e] + a*bg_task[e];
    int e0 = 0;
#pragma unroll
    for (int e = 1; e < 8; ++e) if (lg[e] > lg[e0]) e0 = e;
    int e1 = (e0 == 0) ? 1 : 0;
#pragma unroll
    for (int e = 0; e < 8; ++e) if (e != e0 && lg[e] > lg[e1]) e1 = e;
    float mx = lg[0];
#pragma unroll
    for (int e = 1; e < 8; ++e) mx = fmaxf(mx, lg[e]);
    float p[8], s = 0.0f;
#pragma unroll
    for (int e = 0; e < 8; ++e) { p[e] = __expf(lg[e] - mx); s += p[e]; }
    float inv = 1.0f / s;
#pragma unroll
    for (int e = 0; e < 8; ++e) atomicAdd(&s_wsum[e], p[e] * inv);
    float p1 = __expf(lg[e1] - lg[e0]);
    float w0 = 1.0f / (1.0f + p1);
    float w1 = p1 * w0;
    int pos0 = atomicAdd(&cnt[e0], 1);
    tok_list[e0*NTOK + pos0] = tok; wt_list[e0*NTOK + pos0] = w0;
    int pos1 = atomicAdd(&cnt[e1], 1);
    tok_list[e1*NTOK + pos1] = tok; wt_list[e1*NTOK + pos1] = w1;
  }
  __syncthreads();
  if (tid < NEXP) atomicAdd(&wsum[tid], s_wsum[tid]);
}

// ---------------- finalize: offsets prefix + l_aux ----------------
__global__ void finalize_kernel(const int* __restrict__ cnt, const float* __restrict__ wsum,
                                int* __restrict__ offs, float* __restrict__ laux)
{
  if (threadIdx.x == 0) {
    int o = 0; float l = 0.0f;
    for (int e = 0; e < NEXP; ++e) {
      offs[e] = o; o += cnt[e];
      l += (wsum[e] * (1.0f/NTOK)) * ((float)cnt[e] * (1.0f/NTOK));
    }
    *laux = l;
  }
}

// ---------------- prep: X -> bf16 ----------------
__global__ __launch_bounds__(256) void prep_x(const float* __restrict__ X,
                                              unsigned short* __restrict__ Xb)
{
  size_t i = ((size_t)blockIdx.x*256 + threadIdx.x)*8;
  f32x4 a = *(const f32x4*)(X + i);
  f32x4 b = *(const f32x4*)(X + i + 4);
  u16x8 v;
#pragma unroll
  for (int j = 0; j < 4; ++j) {
    v[j]   = __builtin_bit_cast(unsigned short, (__bf16)a[j]);
    v[4+j] = __builtin_bit_cast(unsigned short, (__bf16)b[j]);
  }
  *(u16x8*)(Xb + i) = v;
}

// ---------------- prep: W -> bf16, transposed [n][k], tile-blocked, swizzled ----
// Tile (kb,J,e): 128 n-rows x 64 k, 16KB each, laid out so a linear
// global_load_lds fill produces LDS[r][c] = W[kb*64 + (c^(r&7))*8 + j][J*128+r].
// PERM (for W2): source k additionally permuted to match H's physical col order.
template<bool PERM>
__global__ __launch_bounds__(256) void prep_w(const float* __restrict__ W,
                                              unsigned short* __restrict__ Wb, int N)
{
  int kb = blockIdx.x, J = blockIdx.y, e = blockIdx.z;
  int NKB = gridDim.x, NJ = gridDim.y;
  int K = NKB*64;
  __shared__ unsigned short t[64*132];

  int tid = threadIdx.x;
  const float* src = W + ((size_t)e*K + (size_t)kb*64) * N + J*128;
#pragma unroll
  for (int i = 0; i < 8; ++i) {
    int k = (tid>>5)*8 + i;
    f32x4 v = *(const f32x4*)(src + (size_t)k*N + (tid&31)*4);
    u16x4 b;
#pragma unroll
    for (int j = 0; j < 4; ++j) b[j] = __builtin_bit_cast(unsigned short, (__bf16)v[j]);
    *(u16x4*)&t[k*132 + (tid&31)*4] = b;
  }
  __syncthreads();

  unsigned short* dst = Wb + ((size_t)(e*NJ + J)*NKB + kb)*8192;
  int c = tid & 7, rr = tid >> 3;
#pragma unroll
  for (int ii = 0; ii < 4; ++ii) {
    int r = rr + 32*ii;
    u16x8 v;
#pragma unroll
    for (int j = 0; j < 8; ++j) {
      int rem = ((c ^ (r&7)) << 3) + j;
      if (PERM) rem = ((rem & 3) << 4) | (rem >> 2);
      v[j] = t[rem*132 + r];
    }
    *(u16x8*)(dst + r*64 + c*8) = v;
  }
}

// ---------------- GEMM1 (fast): H = gelu(gather(Xb) @ W1b + b1) ----------------
// 128x128 tile, BK=64, 4 waves, global_load_lds for A and B, XOR-swizzled LDS.
__global__ __launch_bounds__(256) void gemm1_glds(
    const unsigned short* __restrict__ Xb, const unsigned short* __restrict__ W1b,
    const float* __restrict__ b1,
    const int* __restrict__ cnt, const int* __restrict__ offs,
    const int* __restrict__ tok_list, unsigned short* __restrict__ H)
{
  int e  = blockIdx.z;
  int ce = cnt[e];
  int m0 = blockIdx.x * 128;
  if (m0 >= ce) return;
  int J  = blockIdx.y;
  int off = offs[e];

  __shared__ __align__(16) unsigned short sA[128*64];
  __shared__ __align__(16) unsigned short sB[128*64];
  __shared__ int s_tok[128];

  int tid = threadIdx.x;
  if (tid < 128) {
    int idx = m0 + tid;
    s_tok[tid] = tok_list[e*NTOK + ((idx < ce) ? idx : (ce-1))];
  }
  __syncthreads();

  int w = tid >> 6, l = tid & 63;
  const char* asrc[4];
#pragma unroll
  for (int i = 0; i < 4; ++i) {
    int r = w*32 + i*8 + (l>>3);
    int c = l & 7;
    asrc[i] = (const char*)(Xb + (size_t)s_tok[r]*DDIM) + ((c ^ (r&7)) << 4);
  }
  const char* bsrc = (const char*)W1b + (size_t)(e*32 + J)*16*16384 + w*4096 + l*16;
  unsigned short* aldsw = sA + w*2048;
  unsigned short* bldsw = sB + w*2048;

  f32x4 acc[4][4];
#pragma unroll
  for (int mi = 0; mi < 4; ++mi)
#pragma unroll
    for (int ni = 0; ni < 4; ++ni) acc[mi][ni] = (f32x4){0.f,0.f,0.f,0.f};

  int q = l & 15, g = l >> 4;
  int wr = w >> 1, wc = w & 1;

  for (int ks = 0; ks < DDIM/64; ++ks) {
#pragma unroll
    for (int i = 0; i < 4; ++i) {
      glds16(asrc[i] + ks*128,                  aldsw + i*512);
      glds16(bsrc + (size_t)ks*16384 + i*1024,  bldsw + i*512);
    }
    __syncthreads();
#pragma unroll
    for (int kk = 0; kk < 2; ++kk) {
      int csw = ((kk*4 + g) ^ (q & 7)) << 3;
      bf16x8 af[4], bfv[4];
#pragma unroll
      for (int mi = 0; mi < 4; ++mi) af[mi]  = *(const bf16x8*)&sA[(wr*64 + mi*16 + q)*64 + csw];
#pragma unroll
      for (int ni = 0; ni < 4; ++ni) bfv[ni] = *(const bf16x8*)&sB[(wc*64 + ni*16 + q)*64 + csw];
#pragma unroll
      for (int mi = 0; mi < 4; ++mi)
#pragma unroll
        for (int ni = 0; ni < 4; ++ni)
          acc[mi][ni] = __builtin_amdgcn_mfma_f32_16x16x32_bf16(af[mi], bfv[ni], acc[mi][ni], 0, 0, 0);
    }
    __syncthreads();
  }

  // epilogue: bias+gelu, write H in PERMUTED col order: phys p = base + q*4 + ni
  int n0 = J*128;
  float bias[4];
#pragma unroll
  for (int ni = 0; ni < 4; ++ni) bias[ni] = b1[(size_t)e*FDIM + n0 + wc*64 + ni*16 + q];
#pragma unroll
  for (int mi = 0; mi < 4; ++mi) {
#pragma unroll
    for (int j = 0; j < 4; ++j) {
      int r = wr*64 + mi*16 + g*4 + j;
      if (m0 + r >= ce) continue;
      u16x4 hv;
#pragma unroll
      for (int ni = 0; ni < 4; ++ni) {
        float h = acc[mi][ni][j] + bias[ni];
        hv[ni] = __builtin_bit_cast(unsigned short, (__bf16)gelu_tanh(h));
      }
      *(u16x4*)&H[(size_t)(off + m0 + r)*FDIM + n0 + wc*64 + q*4] = hv;
    }
  }
}

// ---------------- GEMM2 (fast): out[tok] += w * (H @ W2b + b2) ----------------
__global__ __launch_bounds__(256) void gemm2_glds(
    const unsigned short* __restrict__ H, const unsigned short* __restrict__ W2b,
    const float* __restrict__ b2,
    const int* __restrict__ cnt, const int* __restrict__ offs,
    const int* __restrict__ tok_list, const float* __restrict__ wt_list,
    float* __restrict__ out)
{
  int e  = blockIdx.z;
  int ce = cnt[e];
  int m0 = blockIdx.x * 128;
  if (m0 >= ce) return;
  int J  = blockIdx.y;
  int off = offs[e];

  __shared__ __align__(16) unsigned short sA[128*64];
  __shared__ __align__(16) unsigned short sB[128*64];
  __shared__ int   s_tok[128];
  __shared__ float s_wt[128];

  int tid = threadIdx.x;
  if (tid < 128) {
    int idx = m0 + tid;
    int cidx = (idx < ce) ? idx : (ce-1);
    s_tok[tid] = tok_list[e*NTOK + cidx];
    s_wt[tid]  = (idx < ce) ? wt_list[e*NTOK + cidx] : 0.0f;
  }
  __syncthreads();

  int w = tid >> 6, l = tid & 63;
  const char* asrc[4];
#pragma unroll
  for (int i = 0; i < 4; ++i) {
    int r = w*32 + i*8 + (l>>3);
    int rr = (m0 + r < ce) ? r : (ce-1-m0);
    int c = l & 7;
    asrc[i] = (const char*)(H + (size_t)(off + m0 + rr)*FDIM) + ((c ^ (r&7)) << 4);
  }
  const char* bsrc = (const char*)W2b + (size_t)(e*8 + J)*64*16384 + w*4096 + l*16;
  unsigned short* aldsw = sA + w*2048;
  unsigned short* bldsw = sB + w*2048;

  f32x4 acc[4][4];
#pragma unroll
  for (int mi = 0; mi < 4; ++mi)
#pragma unroll
    for (int ni = 0; ni < 4; ++ni) acc[mi][ni] = (f32x4){0.f,0.f,0.f,0.f};

  int q = l & 15, g = l >> 4;
  int wr = w >> 1, wc = w & 1;

  for (int ks = 0; ks < FDIM/64; ++ks) {
#pragma unroll
    for (int i = 0; i < 4; ++i) {
      glds16(asrc[i] + ks*128,                  aldsw + i*512);
      glds16(bsrc + (size_t)ks*16384 + i*1024,  bldsw + i*512);
    }
    __syncthreads();
#pragma unroll
    for (int kk = 0; kk < 2; ++kk) {
      int csw = ((kk*4 + g) ^ (q & 7)) << 3;
      bf16x8 af[4], bfv[4];
#pragma unroll
      for (int mi = 0; mi < 4; ++mi) af[mi]  = *(const bf16x8*)&sA[(wr*64 + mi*16 + q)*64 + csw];
#pragma unroll
      for (int ni = 0; ni < 4; ++ni) bfv[ni] = *(const bf16x8*)&sB[(wc*64 + ni*16 + q)*64 + csw];
#pragma unroll
      for (int mi = 0; mi < 4; ++mi)
#pragma unroll
        for (int ni = 0; ni < 4; ++ni)
          acc[mi][ni] = __builtin_amdgcn_mfma_f32_16x16x32_bf16(af[mi], bfv[ni], acc[mi][ni], 0, 0, 0);
    }
    __syncthreads();
  }

  int n0 = J*128;
  float bias[4];
#pragma unroll
  for (int ni = 0; ni < 4; ++ni) bias[ni] = b2[(size_t)e*DDIM + n0 + wc*64 + ni*16 + q];
#pragma unroll
  for (int mi = 0; mi < 4; ++mi) {
#pragma unroll
    for (int j = 0; j < 4; ++j) {
      int r = wr*64 + mi*16 + g*4 + j;
      if (m0 + r >= ce) continue;
      int tok = s_tok[r];
      float wt = s_wt[r];
      float* orow = out + (size_t)tok * DDIM;
#pragma unroll
      for (int ni = 0; ni < 4; ++ni) {
        float y = acc[mi][ni][j] + bias[ni];
        unsafeAtomicAdd(&orow[n0 + wc*64 + ni*16 + q], wt * y);
      }
    }
  }
}

// ================= FALLBACK (round-2, used only if ws_size too small) =========
__global__ __launch_bounds__(256) void gemm1_fb(
    const float* __restrict__ X, const float* __restrict__ W1,
    const float* __restrict__ b1,
    const int* __restrict__ cnt, const int* __restrict__ offs,
    const int* __restrict__ tok_list,
    unsigned short* __restrict__ H)
{
  int e  = blockIdx.z;
  int ce = cnt[e];
  int m0 = blockIdx.x * 128;
  if (m0 >= ce) return;
  int n0 = blockIdx.y * 128;
  int off = offs[e];
  const float* We = W1 + (size_t)e * DDIM * FDIM;
  const float* be = b1 + (size_t)e * FDIM;

  __shared__ __align__(16) unsigned short sA[128*40];
  __shared__ __align__(16) unsigned short sB[128*40];
  __shared__ int s_tok[128];

  int tid = threadIdx.x;
  if (tid < 128) {
    int idx = m0 + tid;
    s_tok[tid] = (idx < ce) ? tok_list[e*NTOK + idx] : -1;
  }
  __syncthreads();

  int kcA = tid & 3, rA = tid >> 2;
  const float* aptr[2]; bool av[2];
#pragma unroll
  for (int i = 0; i < 2; ++i) {
    int t = s_tok[rA + 64*i];
    av[i]   = (t >= 0);
    aptr[i] = av[i] ? (X + (size_t)t * DDIM + kcA*8) : X;
  }
  int nB = tid & 63, kcB = tid >> 6;

  f32x4 acc[4][4];
#pragma unroll
  for (int mi = 0; mi < 4; ++mi)
#pragma unroll
    for (int ni = 0; ni < 4; ++ni) acc[mi][ni] = (f32x4){0.f,0.f,0.f,0.f};

  int lane = tid & 63, wid = tid >> 6;
  int wr = wid >> 1, wc = wid & 1;
  int q = lane & 15, g = lane >> 4;
  const int arow = (wr*64 + q)*40 + g*8;
  const int brow = (wc*64 + q)*40 + g*8;

  for (int k0 = 0; k0 < DDIM; k0 += 32) {
#pragma unroll
    for (int i = 0; i < 2; ++i) {
      f32x4 va = {0.f,0.f,0.f,0.f}, vb = {0.f,0.f,0.f,0.f};
      if (av[i]) { va = *(const f32x4*)(aptr[i] + k0); vb = *(const f32x4*)(aptr[i] + k0 + 4); }
      bf16x8 bv;
      bv[0]=(__bf16)va[0]; bv[1]=(__bf16)va[1]; bv[2]=(__bf16)va[2]; bv[3]=(__bf16)va[3];
      bv[4]=(__bf16)vb[0]; bv[5]=(__bf16)vb[1]; bv[6]=(__bf16)vb[2]; bv[7]=(__bf16)vb[3];
      *(bf16x8*)&sA[(rA + 64*i)*40 + kcA*8] = bv;
    }
    {
      const float* bsrc2 = We + (size_t)(k0 + kcB*8) * FDIM + n0 + nB;
#pragma unroll
      for (int i = 0; i < 2; ++i) {
        bf16x8 bv;
#pragma unroll
        for (int kk = 0; kk < 8; ++kk) bv[kk] = (__bf16)bsrc2[(size_t)kk*FDIM + 64*i];
        *(bf16x8*)&sB[(nB + 64*i)*40 + kcB*8] = bv;
      }
    }
    __syncthreads();
    bf16x8 af[4], bfr[4];
#pragma unroll
    for (int mi = 0; mi < 4; ++mi) af[mi]  = *(const bf16x8*)&sA[arow + mi*640];
#pragma unroll
    for (int ni = 0; ni < 4; ++ni) bfr[ni] = *(const bf16x8*)&sB[brow + ni*640];
#pragma unroll
    for (int mi = 0; mi < 4; ++mi)
#pragma unroll
      for (int ni = 0; ni < 4; ++ni)
        acc[mi][ni] = __builtin_amdgcn_mfma_f32_16x16x32_bf16(af[mi], bfr[ni], acc[mi][ni], 0, 0, 0);
    __syncthreads();
  }

#pragma unroll
  for (int mi = 0; mi < 4; ++mi) {
    int rit = wr*64 + mi*16 + g*4;
#pragma unroll
    for (int j = 0; j < 4; ++j) {
      int r = m0 + rit + j;
      if (r >= ce) continue;
      size_t hrow = (size_t)(off + r) * FDIM;
#pragma unroll
      for (int ni = 0; ni < 4; ++ni) {
        int n = n0 + wc*64 + ni*16 + q;
        float h = acc[mi][ni][j] + be[n];
        H[hrow + n] = __builtin_bit_cast(unsigned short, (__bf16)gelu_tanh(h));
      }
    }
  }
}

__global__ __launch_bounds__(256) void gemm2_fb(
    const unsigned short* __restrict__ H, const float* __restrict__ W2,
    const float* __restrict__ b2,
    const int* __restrict__ cnt, const int* __restrict__ offs,
    const int* __restrict__ tok_list, const float* __restrict__ wt_list,
    float* __restrict__ out)
{
  int e  = blockIdx.z;
  int ce = cnt[e];
  int m0 = blockIdx.x * 128;
  if (m0 >= ce) return;
  int n0 = blockIdx.y * 128;
  int off = offs[e];
  const float* We = W2 + (size_t)e * FDIM * DDIM;
  const float* be = b2 + (size_t)e * DDIM;

  __shared__ __align__(16) unsigned short sA[128*40];
  __shared__ __align__(16) unsigned short sB[128*40];
  __shared__ int   s_tok[128];
  __shared__ float s_wt[128];

  int tid = threadIdx.x;
  if (tid < 128) {
    int idx = m0 + tid;
    bool v = (idx < ce);
    s_tok[tid] = v ? tok_list[e*NTOK + idx] : 0;
    s_wt[tid]  = v ? wt_list[e*NTOK + idx] : 0.0f;
  }
  __syncthreads();

  int kcA = tid & 3, rA = tid >> 2;
  const unsigned short* aptr[2]; bool av[2];
#pragma unroll
  for (int i = 0; i < 2; ++i) {
    int r = rA + 64*i;
    av[i]   = (m0 + r < ce);
    aptr[i] = H + (size_t)(off + m0 + r) * FDIM + kcA*8;
  }
  int nB = tid & 63, kcB = tid >> 6;

  f32x4 acc[4][4];
#pragma unroll
  for (int mi = 0; mi < 4; ++mi)
#pragma unroll
    for (int ni = 0; ni < 4; ++ni) acc[mi][ni] = (f32x4){0.f,0.f,0.f,0.f};

  int lane = tid & 63, wid = tid >> 6;
  int wr = wid >> 1, wc = wid & 1;
  int q = lane & 15, g = lane >> 4;
  const int arow = (wr*64 + q)*40 + g*8;
  const int brow = (wc*64 + q)*40 + g*8;
  const u16x8 z8 = {0,0,0,0,0,0,0,0};

  for (int k0 = 0; k0 < FDIM; k0 += 32) {
#pragma unroll
    for (int i = 0; i < 2; ++i) {
      u16x8 v = av[i] ? *(const u16x8*)(aptr[i] + k0) : z8;
      *(u16x8*)&sA[(rA + 64*i)*40 + kcA*8] = v;
    }
    {
      const float* bsrc2 = We + (size_t)(k0 + kcB*8) * DDIM + n0 + nB;
#pragma unroll
      for (int i = 0; i < 2; ++i) {
        bf16x8 bv;
#pragma unroll
        for (int kk = 0; kk < 8; ++kk) bv[kk] = (__bf16)bsrc2[(size_t)kk*DDIM + 64*i];
        *(bf16x8*)&sB[(nB + 64*i)*40 + kcB*8] = bv;
      }
    }
    __syncthreads();
    bf16x8 af[4], bfr[4];
#pragma unroll
    for (int mi = 0; mi < 4; ++mi) af[mi]  = *(const bf16x8*)&sA[arow + mi*640];
#pragma unroll
    for (int ni = 0; ni < 4; ++ni) bfr[ni] = *(const bf16x8*)&sB[brow + ni*640];
#pragma unroll
    for (int mi = 0; mi < 4; ++mi)
#pragma unroll
      for (int ni = 0; ni < 4; ++ni)
        acc[mi][ni] = __builtin_amdgcn_mfma_f32_16x16x32_bf16(af[mi], bfr[ni], acc[mi][ni], 0, 0, 0);
    __syncthreads();
  }

#pragma unroll
  for (int mi = 0; mi < 4; ++mi) {
    int rit = wr*64 + mi*16 + g*4;
#pragma unroll
    for (int j = 0; j < 4; ++j) {
      int r = rit + j;
      if (m0 + r >= ce) continue;
      int tok = s_tok[r];
      float wq = s_wt[r];
      float* orow = out + (size_t)tok * DDIM;
#pragma unroll
      for (int ni = 0; ni < 4; ++ni) {
        int n = n0 + wc*64 + ni*16 + q;
        float y = acc[mi][ni][j] + be[n];
        unsafeAtomicAdd(&orow[n], wq * y);
      }
    }
  }
}

// ---------------- launch ----------------
extern "C" void kernel_launch(void* const* d_in, const int* in_sizes, int n_in,
                              void* d_out, int out_size, void* d_ws, size_t ws_size,
                              hipStream_t stream)
{
  const float* x       = (const float*)d_in[0];
  const float* task    = (const float*)d_in[1];
  const float* alpha   = (const float*)d_in[2];
  const float* Wg_in   = (const float*)d_in[3];
  const float* bg_in   = (const float*)d_in[4];
  const float* Wg_task = (const float*)d_in[5];
  const float* bg_task = (const float*)d_in[6];
  const float* W1      = (const float*)d_in[7];
  const float* b1      = (const float*)d_in[8];
  const float* W2      = (const float*)d_in[9];
  const float* b2      = (const float*)d_in[10];
  float* out = (float*)d_out;

  char* ws = (char*)d_ws;
  int*   cnt      = (int*)(ws + 0);
  float* wsum     = (float*)(ws + 32);
  int*   offs     = (int*)(ws + 64);
  int*   tok_list = (int*)(ws + 128);
  float* wt_list  = (float*)(ws + 128 + NTOK*NEXP*4);
  unsigned short* H   = (unsigned short*)(ws + H_OFF);
  unsigned short* W1b = (unsigned short*)(ws + W1B_OFF);
  unsigned short* W2b = (unsigned short*)(ws + W2B_OFF);
  unsigned short* Xb  = (unsigned short*)(ws + XB_OFF);

  hipMemsetAsync(d_out, 0, (size_t)out_size * sizeof(float), stream);
  hipMemsetAsync(ws, 0, 128, stream);
  gate_kernel<<<NTOK/4, 256, 0, stream>>>(x, task, alpha, Wg_in, bg_in, Wg_task, bg_task,
                                          cnt, wsum, tok_list, wt_list);
  finalize_kernel<<<1, 64, 0, stream>>>(cnt, wsum, offs, out + (size_t)NTOK*DDIM);

  if (ws_size >= (size_t)FULL_WS) {
    prep_x<<<NTOK*DDIM/2048, 256, 0, stream>>>(x, Xb);
    prep_w<false><<<dim3(DDIM/64, FDIM/128, NEXP), 256, 0, stream>>>(W1, W1b, FDIM);
    prep_w<true ><<<dim3(FDIM/64, DDIM/128, NEXP), 256, 0, stream>>>(W2, W2b, DDIM);
    gemm1_glds<<<dim3(NTOK/128, FDIM/128, NEXP), 256, 0, stream>>>(Xb, W1b, b1, cnt, offs, tok_list, H);
    gemm2_glds<<<dim3(NTOK/128, DDIM/128, NEXP), 256, 0, stream>>>(H, W2b, b2, cnt, offs, tok_list, wt_list, out);
  } else {
    gemm1_fb<<<dim3(NTOK/128, FDIM/128, NEXP), 256, 0, stream>>>(x, W1, b1, cnt, offs, tok_list, H);
    gemm2_fb<<<dim3(NTOK/128, DDIM/128, NEXP), 256, 0, stream>>>(H, W2, b2, cnt, offs, tok_list, wt_list, out);
  }
}

// Round 4
// 821.772 us; speedup vs baseline: 3.4505x; 1.3731x over previous
//
#include <hip/hip_runtime.h>

#define NTOK 8192     // B*S
#define DDIM 1024
#define FDIM 4096
#define NEXP 8
#define TDIM 64
#define MAXBLK 72     // max sum_e ceil(cnt_e/256) = 71

// ws layout:
#define H_OFF   (1u<<20)
#define W1B_OFF (H_OFF + 134217728u)      // H: 16384 x 4096 bf16 = 128 MiB
#define W2B_OFF (W1B_OFF + 67108864u)     // W1b: 64 MiB
#define XB_OFF  (W2B_OFF + 67108864u)     // W2b: 64 MiB
#define FULL_WS (XB_OFF + 16777216u)      // Xb: 16 MiB

typedef __bf16 bf16x8 __attribute__((ext_vector_type(8)));
typedef unsigned short u16x8 __attribute__((ext_vector_type(8)));
typedef unsigned short u16x4 __attribute__((ext_vector_type(4)));
typedef float f32x4 __attribute__((ext_vector_type(4)));

__device__ __forceinline__ float gelu_tanh(float h) {
  float u = 0.7978845608028654f * (h + 0.044715f * h * h * h);
  float e = __expf(2.0f * u);
  return 0.5f * h * (2.0f - 2.0f / (e + 1.0f));
}

__device__ __forceinline__ void glds16(const void* g, void* l) {
  __builtin_amdgcn_global_load_lds((const __attribute__((address_space(1))) void*)g,
                                   (__attribute__((address_space(3))) void*)l, 16, 0, 0);
}

// ---------------- gating ----------------
__global__ __launch_bounds__(256) void gate_kernel(
    const float* __restrict__ x, const float* __restrict__ task,
    const float* __restrict__ alpha_p,
    const float* __restrict__ Wg_in, const float* __restrict__ bg_in,
    const float* __restrict__ Wg_task, const float* __restrict__ bg_task,
    int* __restrict__ cnt, float* __restrict__ wsum,
    int* __restrict__ tok_list, float* __restrict__ wt_list)
{
  __shared__ float s_wsum[NEXP];
  int tid = threadIdx.x;
  if (tid < NEXP) s_wsum[tid] = 0.0f;
  __syncthreads();

  int lane = tid & 63;
  int wid  = tid >> 6;
  int tok  = blockIdx.x * 4 + wid;
  float a  = alpha_p[0];

  const float* xr = x + (size_t)tok * DDIM;
  float accd[8] = {0,0,0,0,0,0,0,0};
#pragma unroll
  for (int i = 0; i < DDIM/64; ++i) {
    int d = lane + 64*i;
    float xv = xr[d];
    f32x4 wa = *(const f32x4*)(Wg_in + (size_t)d*8);
    f32x4 wb = *(const f32x4*)(Wg_in + (size_t)d*8 + 4);
#pragma unroll
    for (int j = 0; j < 4; ++j) {
      accd[j]   = fmaf(xv, wa[j], accd[j]);
      accd[4+j] = fmaf(xv, wb[j], accd[4+j]);
    }
  }
  float part[8];
  {
    int d = lane;
    float tv = task[(size_t)tok*TDIM + d];
    f32x4 wa = *(const f32x4*)(Wg_task + (size_t)d*8);
    f32x4 wb = *(const f32x4*)(Wg_task + (size_t)d*8 + 4);
#pragma unroll
    for (int j = 0; j < 4; ++j) {
      part[j]   = (1.0f-a)*accd[j]   + a*(tv*wa[j]);
      part[4+j] = (1.0f-a)*accd[4+j] + a*(tv*wb[j]);
    }
  }
#pragma unroll
  for (int e = 0; e < 8; ++e) {
#pragma unroll
    for (int m = 1; m < 64; m <<= 1) part[e] += __shfl_xor(part[e], m);
  }

  if (lane == 0) {
    float lg[8];
#pragma unroll
    for (int e = 0; e < 8; ++e) lg[e] = part[e] + (1.0f-a)*bg_in[e] + a*bg_task[e];
    int e0 = 0;
#pragma unroll
    for (int e = 1; e < 8; ++e) if (lg[e] > lg[e0]) e0 = e;
    int e1 = (e0 == 0) ? 1 : 0;
#pragma unroll
    for (int e = 0; e < 8; ++e) if (e != e0 && lg[e] > lg[e1]) e1 = e;
    float mx = lg[0];
#pragma unroll
    for (int e = 1; e < 8; ++e) mx = fmaxf(mx, lg[e]);
    float p[8], s = 0.0f;
#pragma unroll
    for (int e = 0; e < 8; ++e) { p[e] = __expf(lg[e] - mx); s += p[e]; }
    float inv = 1.0f / s;
#pragma unroll
    for (int e = 0; e < 8; ++e) atomicAdd(&s_wsum[e], p[e] * inv);
    float p1 = __expf(lg[e1] - lg[e0]);
    float w0 = 1.0f / (1.0f + p1);
    float w1 = p1 * w0;
    int pos0 = atomicAdd(&cnt[e0], 1);
    tok_list[e0*NTOK + pos0] = tok; wt_list[e0*NTOK + pos0] = w0;
    int pos1 = atomicAdd(&cnt[e1], 1);
    tok_list[e1*NTOK + pos1] = tok; wt_list[e1*NTOK + pos1] = w1;
  }
  __syncthreads();
  if (tid < NEXP) atomicAdd(&wsum[tid], s_wsum[tid]);
}

// ---------------- finalize: offsets + l_aux + block table ----------------
__global__ void finalize_kernel(const int* __restrict__ cnt, const float* __restrict__ wsum,
                                int* __restrict__ offs, float* __restrict__ laux,
                                int* __restrict__ blk_e, int* __restrict__ blk_m)
{
  if (threadIdx.x == 0) {
    int o = 0; float l = 0.0f; int nb = 0;
    for (int e = 0; e < NEXP; ++e) {
      offs[e] = o;
      for (int m0 = 0; m0 < cnt[e]; m0 += 256) {
        if (nb < MAXBLK) { blk_e[nb] = e; blk_m[nb] = m0; ++nb; }
      }
      l += (wsum[e] * (1.0f/NTOK)) * ((float)cnt[e] * (1.0f/NTOK));
      o += cnt[e];
    }
    for (; nb < MAXBLK; ++nb) blk_e[nb] = -1;
    *laux = l;
  }
}

// ---------------- prep: X -> bf16 ----------------
__global__ __launch_bounds__(256) void prep_x(const float* __restrict__ X,
                                              unsigned short* __restrict__ Xb)
{
  size_t i = ((size_t)blockIdx.x*256 + threadIdx.x)*8;
  f32x4 a = *(const f32x4*)(X + i);
  f32x4 b = *(const f32x4*)(X + i + 4);
  u16x8 v;
#pragma unroll
  for (int j = 0; j < 4; ++j) {
    v[j]   = __builtin_bit_cast(unsigned short, (__bf16)a[j]);
    v[4+j] = __builtin_bit_cast(unsigned short, (__bf16)b[j]);
  }
  *(u16x8*)(Xb + i) = v;
}

// ---------------- prep: W -> bf16, [n][k] tiles 256x64, swizzled ----------------
// Tile (e,J,kb): 32KB; chunk c=(r<<3)|cc at byte c*16 holds
// W[kb*64 + perm((cc^(r&7))*8+j)][J*256+r], j=0..7.
template<bool PERM>
__global__ __launch_bounds__(256) void prep_w(const float* __restrict__ W,
                                              unsigned short* __restrict__ Wb,
                                              int N, int NKB, int NJ)
{
  int kb = blockIdx.x, J = blockIdx.y, e = blockIdx.z;
  int K = NKB*64;
  __shared__ unsigned short t[64*264];
  int tid = threadIdx.x;
  const float* src = W + ((size_t)e*K + (size_t)kb*64) * N + J*256;
  int k = tid >> 2, cg = tid & 3;
#pragma unroll
  for (int ii = 0; ii < 16; ++ii) {
    int n = cg*64 + ii*4;
    f32x4 v = *(const f32x4*)(src + (size_t)k*N + n);
    u16x4 b;
#pragma unroll
    for (int j = 0; j < 4; ++j) b[j] = __builtin_bit_cast(unsigned short, (__bf16)v[j]);
    *(u16x4*)&t[k*264 + n] = b;
  }
  __syncthreads();
  unsigned short* dst = Wb + ((size_t)(e*NJ + J)*NKB + kb)*16384;
#pragma unroll
  for (int i = 0; i < 8; ++i) {
    int c = i*256 + tid;
    int r = c >> 3, cc = c & 7;
    u16x8 v;
#pragma unroll
    for (int j = 0; j < 8; ++j) {
      int kloc = ((cc ^ (r&7)) << 3) + j;
      if (PERM) kloc = ((kloc & 3) << 4) | (kloc >> 2);
      v[j] = t[kloc*264 + r];
    }
    *(u16x8*)(dst + c*8) = v;
  }
}

// ======================= 256x256 2-phase double-buffered GEMMs ==================
// 8 waves (2M x 4N), BK=64, per-wave C=128x64 (acc[8][4]).
// STAGE(next buf) -> COMPUTE(cur buf) -> vmcnt(0) -> s_barrier   (1 barrier/K-tile)

#define STAGE(sa, sb, ks) do {                                              \
  _Pragma("unroll")                                                         \
  for (int i_ = 0; i_ < 4; ++i_) {                                          \
    glds16(asrc[i_] + (size_t)(ks)*128, (char*)(sa) + dstoff[i_]);          \
    glds16(bsrc + (size_t)(ks)*32768 + i_*8192, (char*)(sb) + dstoff[i_]);  \
  }                                                                         \
} while (0)

#define COMPUTE(sa, sb) do {                                                \
  _Pragma("unroll")                                                         \
  for (int kk_ = 0; kk_ < 2; ++kk_) {                                       \
    int csw_ = ((kk_*4 + g) ^ (q & 7)) << 3;                                \
    bf16x8 bfv_[4];                                                         \
    _Pragma("unroll")                                                       \
    for (int ni_ = 0; ni_ < 4; ++ni_)                                       \
      bfv_[ni_] = *(const bf16x8*)&(sb)[(wc*64 + ni_*16 + q)*64 + csw_];    \
    _Pragma("unroll")                                                       \
    for (int mi_ = 0; mi_ < 8; ++mi_) {                                     \
      bf16x8 af_ = *(const bf16x8*)&(sa)[(wr*128 + mi_*16 + q)*64 + csw_];  \
      _Pragma("unroll")                                                     \
      for (int ni_ = 0; ni_ < 4; ++ni_)                                     \
        acc[mi_][ni_] = __builtin_amdgcn_mfma_f32_16x16x32_bf16(af_, bfv_[ni_], acc[mi_][ni_], 0, 0, 0); \
    }                                                                       \
  }                                                                         \
} while (0)

// ---------------- GEMM1: H = gelu(gather(Xb) @ W1b + b1) ----------------
__global__ __launch_bounds__(512) void gemm1_v4(
    const unsigned short* __restrict__ Xb, const unsigned short* __restrict__ W1b,
    const float* __restrict__ b1,
    const int* __restrict__ cnt, const int* __restrict__ offs,
    const int* __restrict__ tok_list,
    const int* __restrict__ blk_e, const int* __restrict__ blk_m,
    unsigned short* __restrict__ H)
{
  int e = blk_e[blockIdx.x];
  if (e < 0) return;
  int m0 = blk_m[blockIdx.x];
  int ce = cnt[e];
  int off = offs[e];
  int J = blockIdx.y;

  __shared__ __align__(16) unsigned short sA0[256*64], sB0[256*64];
  __shared__ __align__(16) unsigned short sA1[256*64], sB1[256*64];
  __shared__ int s_tok[256];

  int tid = threadIdx.x;
  if (tid < 256) {
    int idx = m0 + tid;
    s_tok[tid] = tok_list[e*NTOK + ((idx < ce) ? idx : (ce-1))];
  }
  __syncthreads();

  int w = tid >> 6, l = tid & 63;
  int wr = w >> 2, wc = w & 3;
  int q = l & 15, g = l >> 4;

  const char* asrc[4];
  int dstoff[4];
#pragma unroll
  for (int i = 0; i < 4; ++i) {
    int c = i*512 + tid;
    int r = c >> 3, cc = c & 7;
    asrc[i]  = (const char*)(Xb + (size_t)s_tok[r]*DDIM) + ((cc ^ (r&7)) << 4);
    dstoff[i] = c*16;
  }
  const char* bsrc = (const char*)W1b + ((size_t)(e*16 + J)*16)*32768 + (size_t)tid*16;

  f32x4 acc[8][4];
#pragma unroll
  for (int mi = 0; mi < 8; ++mi)
#pragma unroll
    for (int ni = 0; ni < 4; ++ni) acc[mi][ni] = (f32x4){0.f,0.f,0.f,0.f};

  STAGE(sA0, sB0, 0);
  asm volatile("s_waitcnt vmcnt(0)" ::: "memory");
  __builtin_amdgcn_s_barrier();

#define NK1 (DDIM/64)
  for (int ks = 0; ks < NK1; ks += 2) {
    STAGE(sA1, sB1, ks+1);
    COMPUTE(sA0, sB0);
    asm volatile("s_waitcnt vmcnt(0)" ::: "memory");
    __builtin_amdgcn_s_barrier();
    if (ks + 2 < NK1) STAGE(sA0, sB0, ks+2);
    COMPUTE(sA1, sB1);
    asm volatile("s_waitcnt vmcnt(0)" ::: "memory");
    __builtin_amdgcn_s_barrier();
  }

  // epilogue: bias+gelu, permuted H col order (phys = base + q*4 + ni)
  int n0 = J*256;
  float bias[4];
#pragma unroll
  for (int ni = 0; ni < 4; ++ni) bias[ni] = b1[(size_t)e*FDIM + n0 + wc*64 + ni*16 + q];
#pragma unroll
  for (int mi = 0; mi < 8; ++mi) {
#pragma unroll
    for (int j = 0; j < 4; ++j) {
      int r = wr*128 + mi*16 + g*4 + j;
      if (m0 + r >= ce) continue;
      u16x4 hv;
#pragma unroll
      for (int ni = 0; ni < 4; ++ni) {
        float h = acc[mi][ni][j] + bias[ni];
        hv[ni] = __builtin_bit_cast(unsigned short, (__bf16)gelu_tanh(h));
      }
      *(u16x4*)&H[(size_t)(off + m0 + r)*FDIM + n0 + wc*64 + q*4] = hv;
    }
  }
}

// ---------------- GEMM2: out[tok] += w * (H @ W2b + b2) ----------------
__global__ __launch_bounds__(512) void gemm2_v4(
    const unsigned short* __restrict__ H, const unsigned short* __restrict__ W2b,
    const float* __restrict__ b2,
    const int* __restrict__ cnt, const int* __restrict__ offs,
    const int* __restrict__ tok_list, const float* __restrict__ wt_list,
    const int* __restrict__ blk_e, const int* __restrict__ blk_m,
    float* __restrict__ out)
{
  int e = blk_e[blockIdx.x];
  if (e < 0) return;
  int m0 = blk_m[blockIdx.x];
  int ce = cnt[e];
  int off = offs[e];
  int J = blockIdx.y;

  __shared__ __align__(16) unsigned short sA0[256*64], sB0[256*64];
  __shared__ __align__(16) unsigned short sA1[256*64], sB1[256*64];
  __shared__ int   s_tok[256];
  __shared__ float s_wt[256];

  int tid = threadIdx.x;
  if (tid < 256) {
    int idx = m0 + tid;
    int cidx = (idx < ce) ? idx : (ce-1);
    s_tok[tid] = tok_list[e*NTOK + cidx];
    s_wt[tid]  = (idx < ce) ? wt_list[e*NTOK + cidx] : 0.0f;
  }
  __syncthreads();

  int w = tid >> 6, l = tid & 63;
  int wr = w >> 2, wc = w & 3;
  int q = l & 15, g = l >> 4;

  const char* asrc[4];
  int dstoff[4];
#pragma unroll
  for (int i = 0; i < 4; ++i) {
    int c = i*512 + tid;
    int r = c >> 3, cc = c & 7;
    int rr = (m0 + r < ce) ? r : (ce-1-m0);
    asrc[i]  = (const char*)(H + (size_t)(off + m0 + rr)*FDIM) + ((cc ^ (r&7)) << 4);
    dstoff[i] = c*16;
  }
  const char* bsrc = (const char*)W2b + ((size_t)(e*4 + J)*64)*32768 + (size_t)tid*16;

  f32x4 acc[8][4];
#pragma unroll
  for (int mi = 0; mi < 8; ++mi)
#pragma unroll
    for (int ni = 0; ni < 4; ++ni) acc[mi][ni] = (f32x4){0.f,0.f,0.f,0.f};

  STAGE(sA0, sB0, 0);
  asm volatile("s_waitcnt vmcnt(0)" ::: "memory");
  __builtin_amdgcn_s_barrier();

#define NK2 (FDIM/64)
  for (int ks = 0; ks < NK2; ks += 2) {
    STAGE(sA1, sB1, ks+1);
    COMPUTE(sA0, sB0);
    asm volatile("s_waitcnt vmcnt(0)" ::: "memory");
    __builtin_amdgcn_s_barrier();
    if (ks + 2 < NK2) STAGE(sA0, sB0, ks+2);
    COMPUTE(sA1, sB1);
    asm volatile("s_waitcnt vmcnt(0)" ::: "memory");
    __builtin_amdgcn_s_barrier();
  }

  int n0 = J*256;
  float bias[4];
#pragma unroll
  for (int ni = 0; ni < 4; ++ni) bias[ni] = b2[(size_t)e*DDIM + n0 + wc*64 + ni*16 + q];
#pragma unroll
  for (int mi = 0; mi < 8; ++mi) {
#pragma unroll
    for (int j = 0; j < 4; ++j) {
      int r = wr*128 + mi*16 + g*4 + j;
      if (m0 + r >= ce) continue;
      int tok = s_tok[r];
      float wt = s_wt[r];
      float* orow = out + (size_t)tok * DDIM;
#pragma unroll
      for (int ni = 0; ni < 4; ++ni) {
        float y = acc[mi][ni][j] + bias[ni];
        unsafeAtomicAdd(&orow[n0 + wc*64 + ni*16 + q], wt * y);
      }
    }
  }
}

// ---------------- launch ----------------
extern "C" void kernel_launch(void* const* d_in, const int* in_sizes, int n_in,
                              void* d_out, int out_size, void* d_ws, size_t ws_size,
                              hipStream_t stream)
{
  const float* x       = (const float*)d_in[0];
  const float* task    = (const float*)d_in[1];
  const float* alpha   = (const float*)d_in[2];
  const float* Wg_in   = (const float*)d_in[3];
  const float* bg_in   = (const float*)d_in[4];
  const float* Wg_task = (const float*)d_in[5];
  const float* bg_task = (const float*)d_in[6];
  const float* W1      = (const float*)d_in[7];
  const float* b1      = (const float*)d_in[8];
  const float* W2      = (const float*)d_in[9];
  const float* b2      = (const float*)d_in[10];
  float* out = (float*)d_out;

  char* ws = (char*)d_ws;
  int*   cnt      = (int*)(ws + 0);
  float* wsum     = (float*)(ws + 32);
  int*   offs     = (int*)(ws + 64);
  int*   blk_e    = (int*)(ws + 128);
  int*   blk_m    = (int*)(ws + 512);
  int*   tok_list = (int*)(ws + 4096);
  float* wt_list  = (float*)(ws + 4096 + NTOK*NEXP*4);
  unsigned short* H   = (unsigned short*)(ws + H_OFF);
  unsigned short* W1b = (unsigned short*)(ws + W1B_OFF);
  unsigned short* W2b = (unsigned short*)(ws + W2B_OFF);
  unsigned short* Xb  = (unsigned short*)(ws + XB_OFF);

  hipMemsetAsync(d_out, 0, (size_t)out_size * sizeof(float), stream);
  hipMemsetAsync(ws, 0, 128, stream);
  gate_kernel<<<NTOK/4, 256, 0, stream>>>(x, task, alpha, Wg_in, bg_in, Wg_task, bg_task,
                                          cnt, wsum, tok_list, wt_list);
  finalize_kernel<<<1, 64, 0, stream>>>(cnt, wsum, offs, out + (size_t)NTOK*DDIM, blk_e, blk_m);
  prep_x<<<NTOK*DDIM/2048, 256, 0, stream>>>(x, Xb);
  prep_w<false><<<dim3(16, 16, NEXP), 256, 0, stream>>>(W1, W1b, FDIM, 16, 16);
  prep_w<true ><<<dim3(64,  4, NEXP), 256, 0, stream>>>(W2, W2b, DDIM, 64, 4);
  gemm1_v4<<<dim3(MAXBLK, FDIM/256), 512, 0, stream>>>(Xb, W1b, b1, cnt, offs, tok_list,
                                                       blk_e, blk_m, H);
  gemm2_v4<<<dim3(MAXBLK, DDIM/256), 512, 0, stream>>>(H, W2b, b2, cnt, offs, tok_list, wt_list,
                                                       blk_e, blk_m, out);
}